// Round 3
// baseline (454.240 us; speedup 1.0000x reference)
//
#include <hip/hip_runtime.h>
#include <hip/hip_bf16.h>
#include <stdint.h>

typedef __attribute__((ext_vector_type(8))) __bf16 bf16x8;
typedef __attribute__((ext_vector_type(4))) __bf16 bf16x4;
typedef __attribute__((ext_vector_type(4))) float  f32x4;

#define NTOK   8192
#define DMODEL 1024
#define HDIM   4096
#define NEXP   8

__device__ __forceinline__ void glds16(const void* g, void* l) {
  __builtin_amdgcn_global_load_lds(
      (const __attribute__((address_space(1))) uint32_t*)g,
      (__attribute__((address_space(3))) uint32_t*)l, 16, 0, 0);
}

// ------------------------------------------------------------------ utils
__global__ void zero_cnt_kernel(int* cnt) {
  if (threadIdx.x < NEXP) cnt[threadIdx.x] = 0;
}

// ------------------------------------------- gating + x packing (fused)
// One wave per token. All lanes compute softmax/top-2 redundantly from the
// butterfly-reduced logits; lane 0 scatters the token; every lane then
// writes bf16(x * w) from the x values it already holds in registers.
__global__ __launch_bounds__(256) void moe_gate_pack_kernel(
    const float* __restrict__ x, const float* __restrict__ gw,
    const float* __restrict__ gb, __bf16* __restrict__ xbf,
    int* __restrict__ cnt, int* __restrict__ lists)
{
  const int lane = threadIdx.x & 63;
  const int wv   = threadIdx.x >> 6;
  const int t    = (blockIdx.x << 2) + wv;
  const float* xp = x + (size_t)t * DMODEL;

  float xr[16];
  float acc[NEXP];
#pragma unroll
  for (int e = 0; e < NEXP; ++e) acc[e] = 0.f;

#pragma unroll
  for (int j = 0; j < DMODEL / 64; ++j) {
    const int d = (j << 6) + lane;
    const float xv = xp[d];
    xr[j] = xv;
    const float4 g0 = *(const float4*)(gw + (size_t)d * NEXP);
    const float4 g1 = *(const float4*)(gw + (size_t)d * NEXP + 4);
    acc[0] = fmaf(xv, g0.x, acc[0]);
    acc[1] = fmaf(xv, g0.y, acc[1]);
    acc[2] = fmaf(xv, g0.z, acc[2]);
    acc[3] = fmaf(xv, g0.w, acc[3]);
    acc[4] = fmaf(xv, g1.x, acc[4]);
    acc[5] = fmaf(xv, g1.y, acc[5]);
    acc[6] = fmaf(xv, g1.z, acc[6]);
    acc[7] = fmaf(xv, g1.w, acc[7]);
  }
#pragma unroll
  for (int e = 0; e < NEXP; ++e) {
#pragma unroll
    for (int off = 32; off > 0; off >>= 1)
      acc[e] += __shfl_xor(acc[e], off, 64);
  }
  // all lanes redundantly
  float l[NEXP];
#pragma unroll
  for (int e = 0; e < NEXP; ++e) l[e] = acc[e] + gb[e];
  int i1 = 0; float m1 = l[0];
#pragma unroll
  for (int e = 1; e < NEXP; ++e) if (l[e] > m1) { m1 = l[e]; i1 = e; }
  int i2 = -1; float m2 = -3.402823466e38f;
#pragma unroll
  for (int e = 0; e < NEXP; ++e) if (e != i1 && l[e] > m2) { m2 = l[e]; i2 = e; }
  const int es = i1 > i2 ? i1 : i2;       // reference: last expert in loop wins
  float s = 0.f;
#pragma unroll
  for (int e = 0; e < NEXP; ++e) s += expf(l[e] - m1);
  const float w = expf(l[es] - m1) / s;

  if (lane == 0) {
    const int pos = atomicAdd(&cnt[es], 1);
    lists[(size_t)es * NTOK + pos] = t;
  }
  __bf16* xo = xbf + (size_t)t * DMODEL;
#pragma unroll
  for (int j = 0; j < DMODEL / 64; ++j)
    xo[(j << 6) + lane] = (__bf16)(xr[j] * w);
}

// ------------------------------------------------------------------ pack W
// Transpose src [E][K][N] fp32 -> dst [E][N/128][128 n][K] bf16 (k-contig
// rows, NO baked swizzle; GEMM applies swizzle at glds-source time).
// Coalesced global reads (512B/wave), LDS transpose, coalesced 16B writes.
template<int N, int K>
__global__ __launch_bounds__(256) void pack_w_kernel(
    const float* __restrict__ src, __bf16* __restrict__ dst)
{
  const int k0 = blockIdx.x * 64, np = blockIdx.y, e = blockIdx.z;
  const int t = threadIdx.x;
  __shared__ __bf16 sh[8192];   // 64 k x 128 n, n4 XOR-swizzled by (k&3)

  const float* sp = src + (size_t)e * K * N + (size_t)k0 * N + np * 128;
#pragma unroll
  for (int i = 0; i < 8; ++i) {
    const int id = i * 256 + t;
    const int k = id >> 5, n4 = id & 31;
    const float4 v = *(const float4*)(sp + (size_t)k * N + n4 * 4);
    const int phys = n4 ^ ((k & 3) << 3);
    bf16x4 o; o[0] = (__bf16)v.x; o[1] = (__bf16)v.y;
              o[2] = (__bf16)v.z; o[3] = (__bf16)v.w;
    *(bf16x4*)&sh[k * 128 + phys * 4] = o;
  }
  __syncthreads();

  __bf16* dbase = dst + ((size_t)(e * (N / 128) + np) * 128) * K + k0;
#pragma unroll
  for (int j2 = 0; j2 < 4; ++j2) {
    const int c = j2 * 256 + t;
    const int n = c >> 3, ks8 = c & 7;
    bf16x8 v;
#pragma unroll
    for (int j = 0; j < 8; ++j) {
      const int k = ks8 * 8 + j;
      v[j] = sh[k * 128 + (((n >> 2) ^ ((k & 3) << 3)) << 2) + (n & 3)];
    }
    *(bf16x8*)(dbase + (size_t)n * K + ks8 * 8) = v;
  }
}

// ------------------------------------------------------------------ GEMM
// C[token][n] = A[token] @ B[e] + bias[e]; 128x128 tile, BK=32, 4 waves
// (wave-tile 64x64), 4-stage LDS ring, prefetch depth 3, counted vmcnt.
// LDS rows are 64B (32 bf16) with 16B-slot swizzle slot^((row>>1)&3):
// glds sources are pre-swizzled, ds_read_b128 lands 2 lanes/bank (free).
#define WAITV(N) asm volatile("s_waitcnt vmcnt(" #N ")" ::: "memory")

template<int KSTEPS, int ASTRIDE, int NOUT, bool RELU, typename OutT>
__global__ __launch_bounds__(256, 2) void moe_gemm_kernel(
    const __bf16* __restrict__ Am, const __bf16* __restrict__ Bp,
    const float* __restrict__ bias, const int* __restrict__ cnt,
    const int* __restrict__ lists, OutT* __restrict__ outp)
{
  const int e  = blockIdx.y;
  const int ce = cnt[e];
  const int m0 = blockIdx.z << 7;
  if (m0 >= ce) return;
  const int np = blockIdx.x, n0 = np << 7;
  const int* list = lists + (size_t)e * NTOK;

  const int tid = threadIdx.x, lane = tid & 63, wv = tid >> 6;
  const int wm = wv >> 1, wn = wv & 1;           // wave tile position

  __shared__ alignas(16) __bf16 lds[32768];      // 4 stages x (A 8KB | B 8KB)

  // per-thread staging chunks: 2 A + 2 B (16B each) per stage
  const __bf16* asrc[2];
  const __bf16* bsrc[2];
#pragma unroll
  for (int i = 0; i < 2; ++i) {
    const int c = (wv * 2 + i) * 64 + lane;      // chunk id 0..511
    const int r = c >> 2, p = c & 3;
    const int koff = (p ^ ((r >> 1) & 3)) * 8;   // swizzle-adjusted k offset
    const int rm = m0 + r;
    const int tok = list[rm < ce ? rm : ce - 1];
    asrc[i] = Am + (size_t)tok * ASTRIDE + koff;
    bsrc[i] = Bp + ((size_t)(e * (NOUT / 128) + np) * 128 + r) * ASTRIDE + koff;
  }

  auto stage = [&](int s, int ks) {
    __bf16* base = lds + s * 8192;
#pragma unroll
    for (int i = 0; i < 2; ++i)
      glds16(asrc[i] + ks * 32, base + (wv * 2 + i) * 512);
#pragma unroll
    for (int i = 0; i < 2; ++i)
      glds16(bsrc[i] + ks * 32, base + 4096 + (wv * 2 + i) * 512);
  };

  f32x4 acc[4][4] = {};
  const int rl = lane & 15, sl = lane >> 4;

  auto compute = [&](int s) {
    const char* SB = (const char*)lds + s * 16384;
    bf16x8 af[4], bfv[4];
#pragma unroll
    for (int f = 0; f < 4; ++f) {
      const int r = wm * 64 + f * 16 + rl;
      af[f] = *(const bf16x8*)(SB + r * 64 + ((sl ^ ((r >> 1) & 3)) << 4));
    }
#pragma unroll
    for (int f = 0; f < 4; ++f) {
      const int r = wn * 64 + f * 16 + rl;
      bfv[f] = *(const bf16x8*)(SB + 8192 + r * 64 + ((sl ^ ((r >> 1) & 3)) << 4));
    }
#pragma unroll
    for (int i = 0; i < 4; ++i)
#pragma unroll
      for (int j = 0; j < 4; ++j)
        acc[i][j] = __builtin_amdgcn_mfma_f32_16x16x32_bf16(af[i], bfv[j], acc[i][j], 0, 0, 0);
  };

#define BARPRE  do { __builtin_amdgcn_sched_barrier(0); \
                     __builtin_amdgcn_s_barrier();      \
                     __builtin_amdgcn_sched_barrier(0); } while (0)
#define BARPOST do { __builtin_amdgcn_sched_barrier(0); \
                     __builtin_amdgcn_s_barrier(); } while (0)

  WAITV(0);                       // drain setup loads so vmcnt counting is exact
  stage(0, 0); stage(1, 1); stage(2, 2);

  int ks = 0;
  for (; ks < KSTEPS - 3; ++ks) {
    stage((ks + 3) & 3, ks + 3);
    WAITV(12);
    BARPRE; compute(ks & 3); BARPOST;
  }
  WAITV(8);  BARPRE; compute(ks & 3); BARPOST; ++ks;
  WAITV(4);  BARPRE; compute(ks & 3); BARPOST; ++ks;
  WAITV(0);  BARPRE; compute(ks & 3);

  // epilogue: bias (+relu), scatter rows by token id
  const int cl = lane & 15, rh = (lane >> 4) << 2;
  float bb[4];
#pragma unroll
  for (int j = 0; j < 4; ++j)
    bb[j] = bias[(size_t)e * NOUT + n0 + wn * 64 + j * 16 + cl];
#pragma unroll
  for (int i = 0; i < 4; ++i) {
#pragma unroll
    for (int r = 0; r < 4; ++r) {
      const int gm = m0 + wm * 64 + i * 16 + rh + r;
      if (gm < ce) {
        const int tok = list[gm];
        OutT* op = outp + (size_t)tok * NOUT + n0 + wn * 64;
#pragma unroll
        for (int j = 0; j < 4; ++j) {
          float v = acc[i][j][r] + bb[j];
          if constexpr (RELU) v = fmaxf(v, 0.f);
          op[j * 16 + cl] = (OutT)v;
        }
      }
    }
  }
}

// ------------------------------------------------------------------ launch
extern "C" void kernel_launch(void* const* d_in, const int* in_sizes, int n_in,
                              void* d_out, int out_size, void* d_ws, size_t ws_size,
                              hipStream_t stream)
{
  const float* x  = (const float*)d_in[0];
  const float* gw = (const float*)d_in[1];
  const float* gb = (const float*)d_in[2];
  const float* w1 = (const float*)d_in[3];
  const float* b1 = (const float*)d_in[4];
  const float* w2 = (const float*)d_in[5];
  const float* b2 = (const float*)d_in[6];
  float* out = (float*)d_out;

  char* ws = (char*)d_ws;
  int*    cnt   = (int*)ws;                              // 32 B
  int*    lists = (int*)(ws + 65536);                    // 256 KB
  __bf16* xbf   = (__bf16*)(ws + ((size_t)1   << 20));   // 16 MB
  __bf16* hmat  = (__bf16*)(ws + ((size_t)17  << 20));   // 64 MB
  __bf16* w1p   = (__bf16*)(ws + ((size_t)81  << 20));   // 64 MB
  __bf16* w2p   = (__bf16*)(ws + ((size_t)145 << 20));   // 64 MB

  zero_cnt_kernel<<<1, 64, 0, stream>>>(cnt);
  moe_gate_pack_kernel<<<NTOK / 4, 256, 0, stream>>>(x, gw, gb, xbf, cnt, lists);
  pack_w_kernel<HDIM, DMODEL><<<dim3(DMODEL / 64, HDIM / 128, NEXP), 256, 0, stream>>>(w1, w1p);
  pack_w_kernel<DMODEL, HDIM><<<dim3(HDIM / 64, DMODEL / 128, NEXP), 256, 0, stream>>>(w2, w2p);
  // grid (np, e, m): same-(e,np) blocks differ by a multiple of 8 in linear
  // id -> same XCD -> B-tile L2 reuse.
  moe_gemm_kernel<DMODEL / 32, DMODEL, HDIM, true, __bf16>
      <<<dim3(HDIM / 128, NEXP, NTOK / 128), 256, 0, stream>>>(
          xbf, w1p, b1, cnt, lists, hmat);
  moe_gemm_kernel<HDIM / 32, HDIM, DMODEL, false, float>
      <<<dim3(DMODEL / 128, NEXP, NTOK / 128), 256, 0, stream>>>(
          hmat, w2p, b2, cnt, lists, out);
}